// Round 3
// baseline (598.068 us; speedup 1.0000x reference)
//
#include <hip/hip_runtime.h>
#include <math.h>

// Problem constants
#define Bn  16
#define ICn 16
#define Dn  16
#define Hn  128
#define Wn  128
#define OCn 32
#define DPn 14
#define HPn 126
#define WPn 126

typedef _Float16 half_t;
typedef __attribute__((ext_vector_type(8)))  _Float16 half8;
typedef __attribute__((ext_vector_type(16))) float    float16v;

// Tile: block = 4 waves, each wave owns 1 output row x 32 cols.
// Wave-private staging: 3 input rows x 36 cols x 16 ic, f32.
#define TW 32
#define SROWS 3
#define SCOLS 36            // 9 aligned 16B chunks per (ic,row)
#define REAL_CH 432         // 16 ic * 3 rows * 9 chunks
#define SLOT_CH 448         // padded to 7 DMA instrs * 64 lanes (no overrun)
#define SLOT_B  (SLOT_CH*16)   // 7168 B
#define WSLOT_B (2*SLOT_B)     // 14336 B per wave (2-slot ring)
#define EP_PAD 33
#define EP_B (32*EP_PAD*4)     // 4224 B per wave epilogue patch
#define PLB 65536              // plane stride in x (Hn*Wn*4)

__device__ __forceinline__ void gl_lds16(const void* g, void* l) {
    __builtin_amdgcn_global_load_lds(
        (const __attribute__((address_space(1))) unsigned int*)g,
        (__attribute__((address_space(3))) unsigned int*)l, 16, 0, 0);
}
#define WAITV0 do { asm volatile("s_waitcnt vmcnt(0)" ::: "memory"); } while (0)
#define WAITV7 do { asm volatile("s_waitcnt vmcnt(7)" ::: "memory"); } while (0)

// ---------------------------------------------------------------------------
// Pack weights into B-fragment order for mfma_f32_32x32x16_f16:
//   B-frag: lane l holds B[n = l&31][k = (l>>5)*8 + j], j=0..7  (n=oc, k=ic)
// ---------------------------------------------------------------------------
__global__ void pack_w_kernel(const float* __restrict__ w, half_t* __restrict__ wB) {
    int i = blockIdx.x * 256 + threadIdx.x;      // over 27*64*8 = 13824
    if (i >= 27 * 64 * 8) return;
    int tap = i >> 9;
    int l   = (i >> 3) & 63;
    int j   = i & 7;
    int oc  = l & 31;
    int ic  = ((l >> 5) << 3) + j;
    wB[i] = (half_t)w[(oc * ICn + ic) * 27 + tap];
}

// ---------------------------------------------------------------------------
// One plane: 9 spatial taps; tap feeds acc[A0/A1/A2] for kd=0/1/2 (-1 = skip).
// A-frag: 8 ic f32 at stride 108 floats, RTE-convert to f16 at read.
// Slot layout (f32): [ic (108 fl)][row (36 fl)][col (1 fl)], conflict-free:
// lanes read base + m (all 32 banks), h adds 864 = 0 mod 32.
// ---------------------------------------------------------------------------
template<int A0, int A1, int A2, int FI>
__device__ __forceinline__ void phase_compute(const float* sA, const half8* wf,
                                              float16v (&acc)[3], float16v& mn) {
    __builtin_amdgcn_s_setprio(1);
#pragma unroll
    for (int kh = 0; kh < 3; ++kh) {
#pragma unroll
        for (int kw = 0; kw < 3; ++kw) {
            const float* p = sA + kh * SCOLS + kw;
            half8 a;
#pragma unroll
            for (int j = 0; j < 8; ++j) a[j] = (half_t)p[j * 108];
            const int t = kh * 3 + kw;
            if constexpr (A0 >= 0)
                acc[A0] = __builtin_amdgcn_mfma_f32_32x32x16_f16(a, wf[t],      acc[A0], 0, 0, 0);
            if constexpr (A1 >= 0)
                acc[A1] = __builtin_amdgcn_mfma_f32_32x32x16_f16(a, wf[9 + t],  acc[A1], 0, 0, 0);
            if constexpr (A2 >= 0)
                acc[A2] = __builtin_amdgcn_mfma_f32_32x32x16_f16(a, wf[18 + t], acc[A2], 0, 0, 0);
        }
    }
    __builtin_amdgcn_s_setprio(0);
    if constexpr (FI >= 0) {
#pragma unroll
        for (int r = 0; r < 16; ++r) {
            mn[r] = fminf(mn[r], acc[FI][r]);
            acc[FI][r] = 0.0f;
        }
    }
}

// ---------------------------------------------------------------------------
// Fused conv3d -> min(depth) -> softmax(oc). BARRIER-FREE: each wave runs a
// private pipeline {2-slot LDS ring, 7 DMA/phase, vmcnt(0) sync}. Plane d
// feeds acc[(d-kd)%3]; dp=d-2 retires each phase from d=2.
// vmcnt ledger: prologue issues wf(27)+bias(1)+p0(7)+p1(7); WAITV7 -> p0 in.
// Phase d: compute slot[d&1]; WAITV0 (p(d+1) in); issue p(d+2) -> slot[d&1].
// WAITV0's memory clobber fences ds_reads vs the next DMA refill of the slot.
// ---------------------------------------------------------------------------
__launch_bounds__(256, 2)
__global__ void conv_min_softmax_mfma(const float* __restrict__ x,
                                      const half_t* __restrict__ wB,
                                      const float* __restrict__ bias,
                                      float* __restrict__ out) {
    __shared__ __align__(16) char smem[4 * WSLOT_B + 4 * EP_B];

    const int tid  = threadIdx.x;
    const int lane = tid & 63;
    const int wv   = tid >> 6;

    // XCD-contiguous swizzle (bijective, 2048 % 8 == 0): each XCD gets 256
    // consecutive work ids = 2 whole batch images -> halo re-reads are L2 hits.
    int hlin = blockIdx.x + (blockIdx.y << 2) + (blockIdx.z << 7);   // 0..2047
    int wlin = ((hlin & 7) << 8) + (hlin >> 3);
    const int wpbase = (wlin & 3) << 5;          // 4 col-blocks x 32
    const int hpbase = ((wlin >> 2) & 31) << 2;  // 32 row-blocks x 4
    const int b      = wlin >> 7;
    const int hp     = hpbase + wv;              // this wave's output row

    const char* xb = (const char*)x + ((size_t)b << 24);
    char* wslot = smem + wv * WSLOT_B;

    // ---- per-lane DMA source offsets (plane 0): chunk c = ic*27 + row*9 + cq
    unsigned goff[7];
#pragma unroll
    for (int k = 0; k < 7; ++k) {
        int c = lane + (k << 6); if (c > REAL_CH - 1) c = REAL_CH - 1;   // pad dup
        int ic = c / 27, rem = c - ic * 27;
        int row = rem / 9, cq = rem - row * 9;
        int gr = hp + row;          if (gr > Hn - 1) gr = Hn - 1;        // clamp
        int gc = wpbase + (cq << 2); if (gc > Wn - 4) gc = Wn - 4;       // clamp
        goff[k] = ((unsigned)ic << 20) + ((unsigned)gr << 9) + ((unsigned)gc << 2);
    }
    auto issue = [&](const char* gb, int so) {
        __builtin_amdgcn_sched_barrier(0);
#pragma unroll
        for (int k = 0; k < 7; ++k)
            gl_lds16(gb + goff[k], wslot + so + ((lane + (k << 6)) << 4));
        __builtin_amdgcn_sched_barrier(0);
    };

    // ---- preload 27 tap B-fragments + bias ----
    half8 wf[27];
#pragma unroll
    for (int t = 0; t < 27; ++t)
        wf[t] = *(const half8*)(wB + (((size_t)t << 6) + lane) * 8);
    const float bv = bias[lane & 31];
    __builtin_amdgcn_sched_barrier(0);

    // ---- prologue: issue planes 0,1 into private slots ----
    const char* gp = xb;
    issue(gp, 0);      gp += PLB;     // p0 -> slot0
    issue(gp, SLOT_B); gp += PLB;     // p1 -> slot1

    const int m = lane & 31, h = lane >> 5;
    const float* sA0 = (const float*)wslot + h * 864 + m;
    const float* sA1 = (const float*)(wslot + SLOT_B) + h * 864 + m;

    float16v acc[3], mn;
#pragma unroll
    for (int r = 0; r < 16; ++r) {
        acc[0][r] = 0.0f; acc[1][r] = 0.0f; acc[2][r] = 0.0f;
        mn[r] = INFINITY;
    }

    WAITV7;                            // wf, bias, p0 landed (p1 in flight)

#define PH(A0c, A1c, A2c, FIc, SAc) phase_compute<A0c, A1c, A2c, FIc>(SAc, wf, acc, mn)
    PH( 0,-1,-1,-1, sA0); WAITV0; issue(gp, 0);      gp += PLB;   // d0,  p2
    PH( 1, 0,-1,-1, sA1); WAITV0; issue(gp, SLOT_B); gp += PLB;   // d1,  p3
    PH( 2, 1, 0, 0, sA0); WAITV0; issue(gp, 0);      gp += PLB;   // d2,  p4
    PH( 0, 2, 1, 1, sA1); WAITV0; issue(gp, SLOT_B); gp += PLB;   // d3,  p5
    PH( 1, 0, 2, 2, sA0); WAITV0; issue(gp, 0);      gp += PLB;   // d4,  p6
    PH( 2, 1, 0, 0, sA1); WAITV0; issue(gp, SLOT_B); gp += PLB;   // d5,  p7
    PH( 0, 2, 1, 1, sA0); WAITV0; issue(gp, 0);      gp += PLB;   // d6,  p8
    PH( 1, 0, 2, 2, sA1); WAITV0; issue(gp, SLOT_B); gp += PLB;   // d7,  p9
    PH( 2, 1, 0, 0, sA0); WAITV0; issue(gp, 0);      gp += PLB;   // d8,  p10
    PH( 0, 2, 1, 1, sA1); WAITV0; issue(gp, SLOT_B); gp += PLB;   // d9,  p11
    PH( 1, 0, 2, 2, sA0); WAITV0; issue(gp, 0);      gp += PLB;   // d10, p12
    PH( 2, 1, 0, 0, sA1); WAITV0; issue(gp, SLOT_B); gp += PLB;   // d11, p13
    PH( 0, 2, 1, 1, sA0); WAITV0; issue(gp, 0);      gp += PLB;   // d12, p14
    PH( 1, 0, 2, 2, sA1); WAITV0; issue(gp, SLOT_B);              // d13, p15
    PH(-1, 1, 0, 0, sA0); WAITV0;                                 // d14 (p15 in)
    PH(-1,-1, 1, 1, sA1);                                         // d15
#undef PH

    // ---- epilogue (wave-private, no __syncthreads anywhere) ----
    if (hp < HPn) {
        const int oc = m;
        float* ep = (float*)(smem + 4 * WSLOT_B + wv * EP_B);
#pragma unroll
        for (int reg = 0; reg < 16; ++reg) {
            float v = mn[reg] + bv;
            float mx = v;
#pragma unroll
            for (int off = 1; off < 32; off <<= 1)
                mx = fmaxf(mx, __shfl_xor(mx, off, 64));
            float e = __expf(v - mx);
            float s = e;
#pragma unroll
            for (int off = 1; off < 32; off <<= 1)
                s += __shfl_xor(s, off, 64);
            float pr = e / s;
            int mc = (reg & 3) + ((reg >> 2) << 3) + 4 * h;   // pixel col 0..31
            ep[mc * EP_PAD + oc] = pr;
        }
        asm volatile("s_waitcnt lgkmcnt(0)" ::: "memory");
        __builtin_amdgcn_sched_barrier(0);

        // coalesced stores: per oc, 32 consecutive floats along w
#pragma unroll
        for (int it = 0; it < 16; ++it) {
            int i = (it << 6) + lane;            // 0..1023
            int oc2 = i >> 5, pix = i & 31;
            int wp = wpbase + pix;
            if (wp < WPn)
                out[(((size_t)b * OCn + oc2) * HPn + hp) * WPn + wp] =
                    ep[pix * EP_PAD + oc2];
        }
    }
}

extern "C" void kernel_launch(void* const* d_in, const int* in_sizes, int n_in,
                              void* d_out, int out_size, void* d_ws, size_t ws_size,
                              hipStream_t stream) {
    const float* x    = (const float*)d_in[0];
    const float* w    = (const float*)d_in[1];
    const float* bias = (const float*)d_in[2];
    float* out        = (float*)d_out;
    half_t* wB        = (half_t*)d_ws;

    {
        int n = 27 * 64 * 8;
        pack_w_kernel<<<(n + 255) / 256, 256, 0, stream>>>(w, wB);
    }
    {
        dim3 grid(4,                             // 126/32 col-blocks
                  32,                            // 126/4 row-blocks
                  Bn);
        conv_min_softmax_mfma<<<grid, 256, 0, stream>>>(x, wB, bias, out);
    }
}

// Round 5
// 515.816 us; speedup vs baseline: 1.1595x; 1.1595x over previous
//
#include <hip/hip_runtime.h>
#include <math.h>

// Problem constants
#define Bn  16
#define ICn 16
#define Dn  16
#define Hn  128
#define Wn  128
#define OCn 32
#define DPn 14
#define HPn 126
#define WPn 126

typedef _Float16 half_t;
typedef __attribute__((ext_vector_type(8)))  _Float16 half8;
typedef __attribute__((ext_vector_type(16))) float    float16v;

// Block tile: 4 waves x (1 output row x 32 cols). Cooperative staging.
// Staged region per plane: [ic16][row6][col36] f32 = 864 x 16B chunks, linear.
#define SLOT_B 16384          // 1024 chunk slots (864 real + 160 pad)
#define EP_PAD 33             // epilogue transpose pad (conflict-free)
#define PLB 65536             // depth-plane stride in x, bytes (128*128*4)

__device__ __forceinline__ void gl_lds16(const void* g, void* l) {
    __builtin_amdgcn_global_load_lds(
        (const __attribute__((address_space(1))) unsigned int*)g,
        (__attribute__((address_space(3))) unsigned int*)l, 16, 0, 0);
}
#define WAITV(N) asm volatile("s_waitcnt vmcnt(" #N ")" ::: "memory")
#define SBAR() do { __builtin_amdgcn_sched_barrier(0);                     \
    __builtin_amdgcn_s_barrier(); __builtin_amdgcn_sched_barrier(0); } while(0)

// ---------------------------------------------------------------------------
// Pack weights into B-fragment order for mfma_f32_32x32x16_f16:
//   B-frag: lane l holds B[n = l&31][k = (l>>5)*8 + j], j=0..7  (n=oc, k=ic)
//   wB[tap][lane][j] f16, tap = kd*9 + kh*3 + kw
// ---------------------------------------------------------------------------
__global__ void pack_w_kernel(const float* __restrict__ w, half_t* __restrict__ wB) {
    int i = blockIdx.x * 256 + threadIdx.x;      // over 27*64*8 = 13824
    if (i >= 27 * 64 * 8) return;
    int tap = i >> 9;
    int l   = (i >> 3) & 63;
    int j   = i & 7;
    int oc  = l & 31;
    int ic  = ((l >> 5) << 3) + j;
    wB[i] = (half_t)w[(oc * ICn + ic) * 27 + tap];
}

// ---------------------------------------------------------------------------
// One plane: 9 spatial taps; tap feeds acc[A0/A1/A2] for kd=0/1/2 (-1 = skip).
// A-frag: 8 ic f32 at dword stride 216, offset-immediate ds_read_b32,
// conflict-free (32 lanes -> 32 consecutive dwords; h-half +1728 = 0 mod 32).
// B-frags STREAMED from global wB each phase (L1/L2-resident, 27x16B/wave);
// the laundered lz defeats LICM so they never occupy 108 resident VGPRs.
// ---------------------------------------------------------------------------
template<int A0, int A1, int A2, int FI>
__device__ __forceinline__ void phase_compute(const float* sA, const half_t* wBl,
                                              float16v (&acc)[3], float16v& mn) {
    unsigned lz = 0;
    asm volatile("" : "+v"(lz));                 // fresh each phase: no hoist/CSE
    const half_t* wp = wBl + lz;
    __builtin_amdgcn_s_setprio(1);
#pragma unroll
    for (int kh = 0; kh < 3; ++kh) {
#pragma unroll
        for (int kw = 0; kw < 3; ++kw) {
            half8 a;
#pragma unroll
            for (int j = 0; j < 8; ++j) a[j] = (half_t)sA[j * 216 + kh * 36 + kw];
            const int t = kh * 3 + kw;
            if constexpr (A0 >= 0)
                acc[A0] = __builtin_amdgcn_mfma_f32_32x32x16_f16(a, *(const half8*)(wp + (t     ) * 512), acc[A0], 0, 0, 0);
            if constexpr (A1 >= 0)
                acc[A1] = __builtin_amdgcn_mfma_f32_32x32x16_f16(a, *(const half8*)(wp + (t +  9) * 512), acc[A1], 0, 0, 0);
            if constexpr (A2 >= 0)
                acc[A2] = __builtin_amdgcn_mfma_f32_32x32x16_f16(a, *(const half8*)(wp + (t + 18) * 512), acc[A2], 0, 0, 0);
        }
    }
    __builtin_amdgcn_s_setprio(0);
    if constexpr (FI >= 0) {
#pragma unroll
        for (int r = 0; r < 16; ++r) {
            mn[r] = fminf(mn[r], acc[FI][r]);
            acc[FI][r] = 0.0f;
        }
    }
}

// ---------------------------------------------------------------------------
// Fused conv3d -> min(depth) -> softmax(oc).
// Plane-centric, cooperative 3-slot ring. Phase d: {compute plane d (B
// streamed); issue p(d+2) -> slot (d+2)%3 (freed at barrier d-1); WAITV(4)
// [own 4 DMA of p(d+2) newest -> p(d+1) + all older retired]; s_barrier}.
// ---------------------------------------------------------------------------
__launch_bounds__(256, 3)
__global__ void conv_min_softmax_mfma(const float* __restrict__ x,
                                      const half_t* __restrict__ wB,
                                      const float* __restrict__ bias,
                                      float* __restrict__ out) {
    __shared__ __align__(16) char smem[3 * SLOT_B];

    const int tid  = threadIdx.x;
    const int lane = tid & 63;
    const int wv   = tid >> 6;

    // XCD-contiguous swizzle (bijective: 2048 % 8 == 0): each XCD owns 256
    // consecutive work ids = 2 whole batch images -> halo re-reads L2-local.
    int hlin = blockIdx.x + (blockIdx.y << 2) + (blockIdx.z << 7);   // 0..2047
    int wlin = ((hlin & 7) << 8) + (hlin >> 3);
    const int wpbase = (wlin & 3) << 5;           // 4 col-blocks x 32
    const int hpbase = ((wlin >> 2) & 31) << 2;   // 32 row-blocks x 4
    const int b      = wlin >> 7;
    const int hp     = hpbase + wv;               // this wave's output row

    const char* xb = (const char*)x + ((size_t)b << 24);

    // ---- per-thread DMA source offsets (plane 0), 4 chunks/thread ----
    // chunk c = ic*54 + row*9 + cq; positions >= 864 are pad (source dup'd).
    // x strides (bytes): ic = D*H*W*4 = 1<<20, row = W*4 = 1<<9, col = 4.
    unsigned goff[4];
#pragma unroll
    for (int k = 0; k < 4; ++k) {
        int c = tid + (k << 8); if (c > 863) c = 863;
        int ic = c / 54, rem = c - ic * 54;
        int row = rem / 9, cq = rem - row * 9;
        int gr = hpbase + row;       if (gr > Hn - 1) gr = Hn - 1;   // clamp
        int gc = wpbase + (cq << 2); if (gc > Wn - 4) gc = Wn - 4;   // clamp
        goff[k] = ((unsigned)ic << 20) + ((unsigned)gr << 9) + ((unsigned)gc << 2);
    }
    auto issue4 = [&](const char* gb, int so) {
        __builtin_amdgcn_sched_barrier(0);
#pragma unroll
        for (int k = 0; k < 4; ++k)
            gl_lds16(gb + goff[k], smem + so + ((tid + (k << 8)) << 4));
        __builtin_amdgcn_sched_barrier(0);
    };

    const half_t* wBl = wB + lane * 8;            // per-lane B-frag base
    const float bv = bias[lane & 31];

    // ---- prologue: issue planes 0,1 ----
    const char* gp = xb;
    issue4(gp, 0);          gp += PLB;            // p0 -> slot0
    issue4(gp, SLOT_B);     gp += PLB;            // p1 -> slot1

    // A-read base: dword = (8h+j)*216 + (wv+kh)*36 + (m+kw)
    const int m = lane & 31, h = lane >> 5;
    const int abase = h * 1728 + wv * 36 + m;
    const float* sA0 = (const float*)smem + abase;
    const float* sA1 = sA0 + 4096;
    const float* sA2 = sA0 + 8192;

    float16v acc[3], mn;
#pragma unroll
    for (int r = 0; r < 16; ++r) {
        acc[0][r] = 0.0f; acc[1][r] = 0.0f; acc[2][r] = 0.0f;
        mn[r] = INFINITY;
    }

    WAITV(4);                                     // bias + p0 landed (p1 newest 4)
    SBAR();

#define PHASE_ISS(A0c, A1c, A2c, FIc, SAc, SOc) do {                       \
    phase_compute<A0c, A1c, A2c, FIc>(SAc, wBl, acc, mn);                  \
    issue4(gp, SOc); gp += PLB;                                            \
    WAITV(4); SBAR();                                                      \
} while (0)

    PHASE_ISS(0,-1,-1,-1, sA0, 2 * SLOT_B);       // d0,  p2 -> slot2
    PHASE_ISS(1, 0,-1,-1, sA1, 0);                // d1,  p3 -> slot0
#pragma unroll 1
    for (int t3 = 0; t3 < 4; ++t3) {
        PHASE_ISS(2, 1, 0, 0, sA2, SLOT_B);       // d=2+3t, p -> slot1
        PHASE_ISS(0, 2, 1, 1, sA0, 2 * SLOT_B);   // d=3+3t, p -> slot2
        PHASE_ISS(1, 0, 2, 2, sA1, 0);            // d=4+3t, p -> slot0
    }
    phase_compute<-1, 1, 0, 0>(sA2, wBl, acc, mn);   // d14
    WAITV(0); SBAR();                                // p15 landed
    phase_compute<-1,-1, 1, 1>(sA0, wBl, acc, mn);   // d15
#undef PHASE_ISS

    __syncthreads();                              // slots free -> reuse for ep

    // ---- epilogue: bias + softmax over oc (32-lane shfl), wave-private ----
    if (hp < HPn) {
        const int oc = m;
        float* ep = (float*)smem + wv * (32 * EP_PAD);
#pragma unroll
        for (int reg = 0; reg < 16; ++reg) {
            float v = mn[reg] + bv;
            float mx = v;
#pragma unroll
            for (int off = 1; off < 32; off <<= 1)
                mx = fmaxf(mx, __shfl_xor(mx, off, 64));
            float e = __expf(v - mx);
            float s = e;
#pragma unroll
            for (int off = 1; off < 32; off <<= 1)
                s += __shfl_xor(s, off, 64);
            int mc = (reg & 3) + ((reg >> 2) << 3) + 4 * h;   // pixel col 0..31
            ep[mc * EP_PAD + oc] = e / s;
        }
        asm volatile("s_waitcnt lgkmcnt(0)" ::: "memory");
        __builtin_amdgcn_sched_barrier(0);

        // stores: per oc, 32 consecutive floats along w (128B runs)
#pragma unroll
        for (int it = 0; it < 16; ++it) {
            int i = (it << 6) + lane;             // 0..1023
            int oc2 = i >> 5, pix = i & 31;
            int wp = wpbase + pix;
            if (wp < WPn)
                out[((size_t)(b * OCn + oc2) * HPn + hp) * WPn + wp] =
                    ep[pix * EP_PAD + oc2];
        }
    }
}

extern "C" void kernel_launch(void* const* d_in, const int* in_sizes, int n_in,
                              void* d_out, int out_size, void* d_ws, size_t ws_size,
                              hipStream_t stream) {
    const float* x    = (const float*)d_in[0];
    const float* w    = (const float*)d_in[1];
    const float* bias = (const float*)d_in[2];
    float* out        = (float*)d_out;
    half_t* wB        = (half_t*)d_ws;            // 13824 f16 = 27.6 KB scratch

    {
        int n = 27 * 64 * 8;
        pack_w_kernel<<<(n + 255) / 256, 256, 0, stream>>>(w, wB);
    }
    {
        dim3 grid(4,                              // 126/32 col-blocks
                  32,                             // 126/4 row-blocks
                  Bn);
        conv_min_softmax_mfma<<<grid, 256, 0, stream>>>(x, wB, bias, out);
    }
}